// Round 6
// baseline (480.542 us; speedup 1.0000x reference)
//
#include <hip/hip_runtime.h>
#include <stdint.h>

typedef unsigned short u16;
typedef __bf16 bf16x8 __attribute__((ext_vector_type(8)));
typedef float f32x4 __attribute__((ext_vector_type(4)));

#define GLD16(gp, lp) __builtin_amdgcn_global_load_lds( \
    (__attribute__((address_space(1))) void*)(uintptr_t)(gp), \
    (__attribute__((address_space(3))) void*)(uintptr_t)(lp), 16, 0, 0)

#define WAITVM(N) asm volatile("s_waitcnt vmcnt(" #N ")" ::: "memory")
#define BARRIER() asm volatile("s_barrier" ::: "memory")
#define MM(a, b, c) __builtin_amdgcn_mfma_f32_16x16x32_bf16(a, b, c, 0, 0, 0)

__device__ __forceinline__ u16 f2bf(float f) {
  uint32_t u = __builtin_bit_cast(uint32_t, f);
  u += 0x7FFFu + ((u >> 16) & 1u);
  return (u16)(u >> 16);
}

// ---------------- weight transpose + convert: w[K][N] f32 -> wt[N][K] bf16 ----------
__global__ __launch_bounds__(256) void wtrans(const float* __restrict__ w,
                                              u16* __restrict__ wt, int K, int Nn) {
  __shared__ float tile[64][68];
  const int c0 = blockIdx.x << 6, r0 = blockIdx.y << 6;
  const int t = threadIdx.x, tr = t >> 2, tc = t & 3;
#pragma unroll
  for (int p = 0; p < 4; ++p) {
    float4 v = *(const float4*)&w[(size_t)(r0 + tr) * Nn + c0 + tc * 4 + p * 16];
    tile[tr][tc * 4 + p * 16 + 0] = v.x;
    tile[tr][tc * 4 + p * 16 + 1] = v.y;
    tile[tr][tc * 4 + p * 16 + 2] = v.z;
    tile[tr][tc * 4 + p * 16 + 3] = v.w;
  }
  __syncthreads();
#pragma unroll
  for (int p = 0; p < 4; ++p) {
    u16 e0 = f2bf(tile[tc * 4 + p * 16 + 0][tr]);
    u16 e1 = f2bf(tile[tc * 4 + p * 16 + 1][tr]);
    u16 e2 = f2bf(tile[tc * 4 + p * 16 + 2][tr]);
    u16 e3 = f2bf(tile[tc * 4 + p * 16 + 3][tr]);
    uint2 o;
    o.x = (uint32_t)e0 | ((uint32_t)e1 << 16);
    o.y = (uint32_t)e2 | ((uint32_t)e3 << 16);
    *(uint2*)&wt[(size_t)(c0 + tr) * K + r0 + tc * 4 + p * 16] = o;
  }
}

// ---------------- LayerNorm: x[M][1024] f32 -> out bf16 ----------------------------
__global__ __launch_bounds__(256) void lnorm(const float* x, const float* __restrict__ g,
                                             const float* __restrict__ bta,
                                             u16* __restrict__ out) {
  const int lane = threadIdx.x & 63, wid = threadIdx.x >> 6;
  const size_t token = (size_t)blockIdx.x * 4 + wid;
  const float* row = x + token * 1024;
  float v[16];
#pragma unroll
  for (int i = 0; i < 4; ++i) {
    float4 f = *(const float4*)&row[(lane + i * 64) * 4];
    v[i * 4 + 0] = f.x; v[i * 4 + 1] = f.y; v[i * 4 + 2] = f.z; v[i * 4 + 3] = f.w;
  }
  float s = 0.f, s2 = 0.f;
#pragma unroll
  for (int i = 0; i < 16; ++i) { s += v[i]; s2 += v[i] * v[i]; }
  for (int off = 1; off < 64; off <<= 1) {
    s += __shfl_xor(s, off);
    s2 += __shfl_xor(s2, off);
  }
  const float mu = s * (1.0f / 1024.0f);
  const float var = s2 * (1.0f / 1024.0f) - mu * mu;
  const float rstd = rsqrtf(var + 1e-6f);
  u16* orow = out + token * 1024;
#pragma unroll
  for (int i = 0; i < 4; ++i) {
    const int c = (lane + i * 64) * 4;
    float4 gv = *(const float4*)&g[c];
    float4 bv = *(const float4*)&bta[c];
    u16 e0 = f2bf((v[i * 4 + 0] - mu) * rstd * gv.x + bv.x);
    u16 e1 = f2bf((v[i * 4 + 1] - mu) * rstd * gv.y + bv.y);
    u16 e2 = f2bf((v[i * 4 + 2] - mu) * rstd * gv.z + bv.z);
    u16 e3 = f2bf((v[i * 4 + 3] - mu) * rstd * gv.w + bv.w);
    uint2 o;
    o.x = (uint32_t)e0 | ((uint32_t)e1 << 16);
    o.y = (uint32_t)e2 | ((uint32_t)e3 << 16);
    *(uint2*)&orow[c] = o;
  }
}

// ---------------- big-wave-tile GEMM: C[M][N] = A[M][K] * Bt[N][K]^T ---------------
// BM=BN=256, BK=32, 8 waves (2M x 4N), wave-tile 128x64 -> 32 MFMA + 12 ds_read
// per wave per K-tile. 4-slot LDS ring (128 KB), stage K-tile t+2 at iter-t start,
// ONE barrier + ONE counted vmcnt(4) per iter (waits only for loads issued a full
// iter earlier; vmcnt(0) only at tail). Conflict-free chunk swizzle (round-5,
// PMC-verified 0 conflicts): phys16B-chunk = logical ^ ((row>>1)&3).
// EPI 0: +bias (cols<qlimit scaled) -> bf16 ; 1: +bias GELU -> bf16 ;
// EPI 3: f32 atomicAdd into Cout (+bias only when blockIdx.y==0) -- split-K.
template <int EPI>
__global__ __launch_bounds__(512, 2) void gemmk(const u16* __restrict__ A,
                                                const u16* __restrict__ Bt,
                                                const float* __restrict__ bias,
                                                void* Cout, int Ndim, int K, int nT,
                                                float qscale, int qlimit, int gn) {
  __shared__ __align__(16) u16 lds[4][16384];  // 4 slots x (A 16KB + B 16KB)
  const int tid = threadIdx.x, lane = tid & 63, wid = tid >> 6;
  const int wm = wid >> 2, wn = wid & 3;

  const int wg = blockIdx.x;
  const int swz = (wg & 7) * ((int)gridDim.x >> 3) + (wg >> 3);
  const int mblk = swz / gn, nb = swz - mblk * gn;
  const int m0 = mblk << 8, n0 = nb << 8;
  const int koff = blockIdx.y * (nT << 5);

  // staging: thread t -> row t>>2 (+128 for instr1), phys chunk t&3,
  // global sub-chunk = (t&3) ^ ((t>>3)&3)
  const int srow = tid >> 2;
  const int gsub = (tid & 3) ^ ((tid >> 3) & 3);
  const u16* Ag = A + koff + (size_t)(m0 + srow) * K + gsub * 8;
  const u16* Bg = Bt + koff + (size_t)(n0 + srow) * K + gsub * 8;
  const size_t rstep = (size_t)128 * K;
  char* lb = (char*)&lds[0][0];

  // fragment reads: row = base + rrow, phys chunk = g ^ ((rrow>>1)&3)
  const int rrow = lane & 15, g = lane >> 4;
  const int xg = g ^ ((rrow >> 1) & 3);
  const int aoff = (wm * 128 + rrow) * 64 + xg * 16;           // byte, + mf*1024
  const int boff = 16384 + (wn * 64 + rrow) * 64 + xg * 16;    // byte, + nf*1024

  const f32x4 fzero = {0.f, 0.f, 0.f, 0.f};
  f32x4 acc[8][4];
#pragma unroll
  for (int i = 0; i < 8; ++i)
#pragma unroll
    for (int j = 0; j < 4; ++j) acc[i][j] = fzero;

#define STG(tt) do { \
    char* d_ = lb + ((tt) & 3) * 32768; \
    GLD16(Ag + (size_t)(tt) * 32, d_ + tid * 16); \
    GLD16(Ag + rstep + (size_t)(tt) * 32, d_ + 8192 + tid * 16); \
    GLD16(Bg + (size_t)(tt) * 32, d_ + 16384 + tid * 16); \
    GLD16(Bg + rstep + (size_t)(tt) * 32, d_ + 24576 + tid * 16); \
  } while (0)

  STG(0);
  STG(1);
  WAITVM(4);   // S(0) landed (S(1) stays in flight)
  BARRIER();
  for (int t = 0; t < nT; ++t) {
    if (t + 2 < nT) STG(t + 2);
    const char* sb = lb + (t & 3) * 32768;
    bf16x8 bfr[4], af[8];
#pragma unroll
    for (int nf = 0; nf < 4; ++nf)
      bfr[nf] = *(const bf16x8*)(sb + boff + nf * 1024);
#pragma unroll
    for (int mf = 0; mf < 8; ++mf)
      af[mf] = *(const bf16x8*)(sb + aoff + mf * 1024);
    __builtin_amdgcn_s_setprio(1);
#pragma unroll
    for (int mf = 0; mf < 8; ++mf)
#pragma unroll
      for (int nf = 0; nf < 4; ++nf)
        acc[mf][nf] = MM(af[mf], bfr[nf], acc[mf][nf]);
    __builtin_amdgcn_s_setprio(0);
    if (t + 1 < nT) {
      if (t < nT - 2) { WAITVM(4); } else { WAITVM(0); }
      BARRIER();
    }
  }
#undef STG

  const int g4 = (lane >> 4) << 2;
#pragma unroll
  for (int nf = 0; nf < 4; ++nf) {
    const int col = n0 + wn * 64 + nf * 16 + rrow;
    const float bvb = (EPI == 3 && blockIdx.y != 0) ? 0.0f : bias[col];
    const float csf = (EPI == 0 && col < qlimit) ? qscale : 1.0f;
#pragma unroll
    for (int mf = 0; mf < 8; ++mf) {
#pragma unroll
      for (int r = 0; r < 4; ++r) {
        const int row = m0 + wm * 128 + mf * 16 + g4 + r;
        float v = acc[mf][nf][r] + bvb;
        if (EPI == 0) v *= csf;
        if (EPI == 1) v = 0.5f * v * (1.0f + erff(v * 0.70710678118654752f));
        if (EPI == 3) {
          atomicAdd((float*)Cout + (size_t)row * Ndim + col, v);
        } else {
          ((u16*)Cout)[(size_t)row * Ndim + col] = f2bf(v);
        }
      }
    }
  }
}

// ---------------- V transpose: qkv V block -> vt[bh][d][n] bf16 --------------------
__global__ __launch_bounds__(256) void vtrans(const u16* __restrict__ qkv,
                                              u16* __restrict__ vt) {
  const int bh = blockIdx.y, b = bh >> 4, h = bh & 15;
  const int n0 = blockIdx.x << 6;
  __shared__ __align__(16) u16 tile[64][72];
  const int t = threadIdx.x, r = t >> 2, c = t & 3;
  const u16* src = qkv + (size_t)((b << 10) + n0 + r) * 3072 + 2048 + (h << 6);
#pragma unroll
  for (int p = 0; p < 2; ++p)
    *(uint4*)&tile[r][(c * 2 + p) * 8] = *(const uint4*)(src + (c * 2 + p) * 8);
  __syncthreads();
  u16* dst = vt + (size_t)((bh << 6) + r) * 1024 + n0;
#pragma unroll
  for (int p = 0; p < 2; ++p) {
    u16 o[8];
#pragma unroll
    for (int j = 0; j < 8; ++j) o[j] = tile[(c * 2 + p) * 8 + j][r];
    uint4 w;
    w.x = (uint32_t)o[0] | ((uint32_t)o[1] << 16);
    w.y = (uint32_t)o[2] | ((uint32_t)o[3] << 16);
    w.z = (uint32_t)o[4] | ((uint32_t)o[5] << 16);
    w.w = (uint32_t)o[6] | ((uint32_t)o[7] << 16);
    *(uint4*)&dst[(c * 2 + p) * 8] = w;
  }
}

// ---------------- flash attention (no-max softmax, swapped QK^T) -------------------
__global__ __launch_bounds__(256) void attn64(const u16* __restrict__ qkv,
                                              const u16* __restrict__ vt,
                                              u16* __restrict__ aout) {
  const int bh = blockIdx.y, b = bh >> 4, h = bh & 15;
  const int q0 = blockIdx.x << 6;
  const int tid = threadIdx.x, lane = tid & 63, wid = tid >> 6;
  __shared__ __align__(16) u16 kl[4096];
  __shared__ __align__(16) u16 vl[4096];
  __shared__ __align__(16) u16 pl[4][1152];  // [wave][16 q][72]: P rows, k-major

  const int rrow = lane & 15;
  const int g = lane >> 4;
  const u16* qrow = qkv + (size_t)((b << 10) + q0 + (wid << 4) + rrow) * 3072 + (h << 6);
  bf16x8 qf0 = *(const bf16x8*)(qrow + (g << 3));
  bf16x8 qf1 = *(const bf16x8*)(qrow + 32 + (g << 3));

  const int sr = lane >> 3;
  const int lc = (lane & 7) ^ sr;
  const u16* kbase = qkv + (size_t)(b << 10) * 3072 + 1024 + (h << 6) +
                     (size_t)(16 * wid + sr) * 3072 + lc * 8;
  const u16* vbase = vt + (size_t)(bh << 6) * 1024 + (size_t)(16 * wid + sr) * 1024 + lc * 8;

  const f32x4 fzero = {0.f, 0.f, 0.f, 0.f};
  f32x4 oacc[4];
#pragma unroll
  for (int i = 0; i < 4; ++i) oacc[i] = fzero;
  f32x4 lacc = fzero;
  const int rcb = lane & 7;
  u16* plw = &pl[wid][0];

  for (int t = 0; t < 16; ++t) {
    const int kt0 = t << 6;
    GLD16(kbase + (size_t)kt0 * 3072, &kl[(2 * wid + 0) * 512]);
    GLD16(kbase + (size_t)kt0 * 3072 + 8 * 3072, &kl[(2 * wid + 1) * 512]);
    GLD16(vbase + kt0, &vl[(2 * wid + 0) * 512]);
    GLD16(vbase + kt0 + 8 * 1024, &vl[(2 * wid + 1) * 512]);
    __syncthreads();

    f32x4 s4[4];
#pragma unroll
    for (int i = 0; i < 4; ++i) s4[i] = fzero;
#pragma unroll
    for (int nf = 0; nf < 4; ++nf) {
      bf16x8 k0 = *(const bf16x8*)((const char*)kl + (nf * 16 + rrow) * 128 +
                                   ((g + 0) ^ rcb) * 16);
      bf16x8 k1 = *(const bf16x8*)((const char*)kl + (nf * 16 + rrow) * 128 +
                                   ((g + 4) ^ rcb) * 16);
      s4[nf] = __builtin_amdgcn_mfma_f32_16x16x32_bf16(k0, qf0, s4[nf], 0, 0, 0);
      s4[nf] = __builtin_amdgcn_mfma_f32_16x16x32_bf16(k1, qf1, s4[nf], 0, 0, 0);
    }

#pragma unroll
    for (int nf = 0; nf < 4; ++nf) {
      float p0 = exp2f(s4[nf][0]);
      float p1 = exp2f(s4[nf][1]);
      float p2 = exp2f(s4[nf][2]);
      float p3 = exp2f(s4[nf][3]);
      f32x4 pv = {p0, p1, p2, p3};
      lacc += pv;
      uint32_t a0 = __builtin_bit_cast(uint32_t, p0) + 0x8000u;
      uint32_t a1 = __builtin_bit_cast(uint32_t, p1) + 0x8000u;
      uint32_t a2 = __builtin_bit_cast(uint32_t, p2) + 0x8000u;
      uint32_t a3 = __builtin_bit_cast(uint32_t, p3) + 0x8000u;
      uint2 w;
      w.x = __builtin_amdgcn_perm(a1, a0, 0x07060302);
      w.y = __builtin_amdgcn_perm(a3, a2, 0x07060302);
      *(uint2*)(plw + rrow * 72 + nf * 16 + (g << 2)) = w;
    }

    bf16x8 pf0 = *(const bf16x8*)((const char*)plw + rrow * 144 + (g << 4));
    bf16x8 pf1 = *(const bf16x8*)((const char*)plw + rrow * 144 + (g << 4) + 64);
#pragma unroll
    for (int nf = 0; nf < 4; ++nf) {
      bf16x8 v0 = *(const bf16x8*)((const char*)vl + (nf * 16 + rrow) * 128 +
                                   ((g + 0) ^ rcb) * 16);
      bf16x8 v1 = *(const bf16x8*)((const char*)vl + (nf * 16 + rrow) * 128 +
                                   ((g + 4) ^ rcb) * 16);
      oacc[nf] = __builtin_amdgcn_mfma_f32_16x16x32_bf16(pf0, v0, oacc[nf], 0, 0, 0);
      oacc[nf] = __builtin_amdgcn_mfma_f32_16x16x32_bf16(pf1, v1, oacc[nf], 0, 0, 0);
    }
    __syncthreads();
  }

  float lsum = lacc[0] + lacc[1] + lacc[2] + lacc[3];
  lsum += __shfl_xor(lsum, 16);
  lsum += __shfl_xor(lsum, 32);
  const float inv = 1.0f / lsum;
  float invq[4];
#pragma unroll
  for (int r = 0; r < 4; ++r) {
    int bi = __builtin_amdgcn_ds_bpermute(((g << 2) + r) << 2,
                                          __builtin_bit_cast(int, inv));
    invq[r] = __builtin_bit_cast(float, bi);
  }
  u16* ob = aout + (size_t)((b << 10) + q0 + (wid << 4)) * 1024 + (h << 6);
#pragma unroll
  for (int nf = 0; nf < 4; ++nf)
#pragma unroll
    for (int r = 0; r < 4; ++r)
      ob[(size_t)(g * 4 + r) * 1024 + nf * 16 + rrow] = f2bf(oacc[nf][r] * invq[r]);
}

// ---------------- launcher ---------------------------------------------------------
extern "C" void kernel_launch(void* const* d_in, const int* in_sizes, int n_in,
                              void* d_out, int out_size, void* d_ws, size_t ws_size,
                              hipStream_t stream) {
  const float* x = (const float*)d_in[0];
  const float* ln1_g = (const float*)d_in[1];
  const float* ln1_b = (const float*)d_in[2];
  const float* w_qkv = (const float*)d_in[3];
  const float* b_qkv = (const float*)d_in[4];
  const float* w_o = (const float*)d_in[5];
  const float* b_o = (const float*)d_in[6];
  const float* ln2_g = (const float*)d_in[7];
  const float* ln2_b = (const float*)d_in[8];
  const float* w_fc1 = (const float*)d_in[9];
  const float* b_fc1 = (const float*)d_in[10];
  const float* w_fc2 = (const float*)d_in[11];
  const float* b_fc2 = (const float*)d_in[12];
  float* out = (float*)d_out;

  char* w = (char*)d_ws;
  u16* wqkvT = (u16*)w; w += (size_t)3072 * 1024 * 2;
  u16* woT   = (u16*)w; w += (size_t)1024 * 1024 * 2;
  u16* wfc1T = (u16*)w; w += (size_t)4096 * 1024 * 2;
  u16* wfc2T = (u16*)w; w += (size_t)1024 * 4096 * 2;
  u16* xn    = (u16*)w; w += (size_t)8192 * 1024 * 2;
  u16* qkvb  = (u16*)w; w += (size_t)8192 * 3072 * 2;
  u16* vtb   = (u16*)w; w += (size_t)128 * 64 * 1024 * 2;
  u16* attnb = (u16*)w; w += (size_t)8192 * 1024 * 2;
  u16* hbuf  = qkvb;  // overlay: qkv+vt dead when h is produced (64 MB)

  const float QS = 0.18033688011112042f;  // 0.125 * log2(e)

  wtrans<<<dim3(48, 16), 256, 0, stream>>>(w_qkv, wqkvT, 1024, 3072);
  wtrans<<<dim3(16, 16), 256, 0, stream>>>(w_o, woT, 1024, 1024);
  wtrans<<<dim3(64, 16), 256, 0, stream>>>(w_fc1, wfc1T, 1024, 4096);
  wtrans<<<dim3(16, 64), 256, 0, stream>>>(w_fc2, wfc2T, 4096, 1024);

  lnorm<<<2048, 256, 0, stream>>>(x, ln1_g, ln1_b, xn);
  // QKV: M=8192 N=3072 K=1024 -> bf16 qkvb (Q pre-scaled)
  gemmk<0><<<dim3(384, 1), 512, 0, stream>>>(xn, wqkvT, b_qkv, qkvb, 3072, 1024, 32, QS, 1024, 12);
  vtrans<<<dim3(16, 128), 256, 0, stream>>>(qkvb, vtb);
  attn64<<<dim3(16, 128), 256, 0, stream>>>(qkvb, vtb, attnb);
  // proj split-K=2: out = x, then atomic += attn*Wo + b_o
  hipMemcpyAsync(out, x, (size_t)8192 * 1024 * 4, hipMemcpyDeviceToDevice, stream);
  gemmk<3><<<dim3(128, 2), 512, 0, stream>>>(attnb, woT, b_o, out, 1024, 1024, 16, 1.f, 0, 4);
  lnorm<<<2048, 256, 0, stream>>>(out, ln2_g, ln2_b, xn);
  // FC1: M=8192 N=4096 K=1024 -> bf16 hbuf (GELU)
  gemmk<1><<<dim3(512, 1), 512, 0, stream>>>(xn, wfc1T, b_fc1, hbuf, 4096, 1024, 32, 1.f, 0, 16);
  // FC2 split-K=2: out (holds x2 residual) atomic += h*Wfc2 + b_fc2
  gemmk<3><<<dim3(128, 2), 512, 0, stream>>>(hbuf, wfc2T, b_fc2, out, 1024, 4096, 64, 1.f, 0, 4);
}

// Round 7
// 477.183 us; speedup vs baseline: 1.0070x; 1.0070x over previous
//
#include <hip/hip_runtime.h>
#include <stdint.h>

typedef unsigned short u16;
typedef __bf16 bf16x8 __attribute__((ext_vector_type(8)));
typedef float f32x4 __attribute__((ext_vector_type(4)));

#define GLD16(gp, lp) __builtin_amdgcn_global_load_lds( \
    (__attribute__((address_space(1))) void*)(uintptr_t)(gp), \
    (__attribute__((address_space(3))) void*)(uintptr_t)(lp), 16, 0, 0)

#define WAITVM(N) asm volatile("s_waitcnt vmcnt(" #N ")" ::: "memory")
#define BARRIER() asm volatile("s_barrier" ::: "memory")
#define MM(a, b, c) __builtin_amdgcn_mfma_f32_16x16x32_bf16(a, b, c, 0, 0, 0)

__device__ __forceinline__ u16 f2bf(float f) {
  uint32_t u = __builtin_bit_cast(uint32_t, f);
  u += 0x7FFFu + ((u >> 16) & 1u);
  return (u16)(u >> 16);
}

// ---------------- weight transpose + convert: w[K][N] f32 -> wt[N][K] bf16 ----------
__global__ __launch_bounds__(256) void wtrans(const float* __restrict__ w,
                                              u16* __restrict__ wt, int K, int Nn) {
  __shared__ float tile[64][68];
  const int c0 = blockIdx.x << 6, r0 = blockIdx.y << 6;
  const int t = threadIdx.x, tr = t >> 2, tc = t & 3;
#pragma unroll
  for (int p = 0; p < 4; ++p) {
    float4 v = *(const float4*)&w[(size_t)(r0 + tr) * Nn + c0 + tc * 4 + p * 16];
    tile[tr][tc * 4 + p * 16 + 0] = v.x;
    tile[tr][tc * 4 + p * 16 + 1] = v.y;
    tile[tr][tc * 4 + p * 16 + 2] = v.z;
    tile[tr][tc * 4 + p * 16 + 3] = v.w;
  }
  __syncthreads();
#pragma unroll
  for (int p = 0; p < 4; ++p) {
    u16 e0 = f2bf(tile[tc * 4 + p * 16 + 0][tr]);
    u16 e1 = f2bf(tile[tc * 4 + p * 16 + 1][tr]);
    u16 e2 = f2bf(tile[tc * 4 + p * 16 + 2][tr]);
    u16 e3 = f2bf(tile[tc * 4 + p * 16 + 3][tr]);
    uint2 o;
    o.x = (uint32_t)e0 | ((uint32_t)e1 << 16);
    o.y = (uint32_t)e2 | ((uint32_t)e3 << 16);
    *(uint2*)&wt[(size_t)(c0 + tr) * K + r0 + tc * 4 + p * 16] = o;
  }
}

// ---------------- LayerNorm: x[M][1024] f32 -> out bf16 ----------------------------
__global__ __launch_bounds__(256) void lnorm(const float* x, const float* __restrict__ g,
                                             const float* __restrict__ bta,
                                             u16* __restrict__ out) {
  const int lane = threadIdx.x & 63, wid = threadIdx.x >> 6;
  const size_t token = (size_t)blockIdx.x * 4 + wid;
  const float* row = x + token * 1024;
  float v[16];
#pragma unroll
  for (int i = 0; i < 4; ++i) {
    float4 f = *(const float4*)&row[(lane + i * 64) * 4];
    v[i * 4 + 0] = f.x; v[i * 4 + 1] = f.y; v[i * 4 + 2] = f.z; v[i * 4 + 3] = f.w;
  }
  float s = 0.f, s2 = 0.f;
#pragma unroll
  for (int i = 0; i < 16; ++i) { s += v[i]; s2 += v[i] * v[i]; }
  for (int off = 1; off < 64; off <<= 1) {
    s += __shfl_xor(s, off);
    s2 += __shfl_xor(s2, off);
  }
  const float mu = s * (1.0f / 1024.0f);
  const float var = s2 * (1.0f / 1024.0f) - mu * mu;
  const float rstd = rsqrtf(var + 1e-6f);
  u16* orow = out + token * 1024;
#pragma unroll
  for (int i = 0; i < 4; ++i) {
    const int c = (lane + i * 64) * 4;
    float4 gv = *(const float4*)&g[c];
    float4 bv = *(const float4*)&bta[c];
    u16 e0 = f2bf((v[i * 4 + 0] - mu) * rstd * gv.x + bv.x);
    u16 e1 = f2bf((v[i * 4 + 1] - mu) * rstd * gv.y + bv.y);
    u16 e2 = f2bf((v[i * 4 + 2] - mu) * rstd * gv.z + bv.z);
    u16 e3 = f2bf((v[i * 4 + 3] - mu) * rstd * gv.w + bv.w);
    uint2 o;
    o.x = (uint32_t)e0 | ((uint32_t)e1 << 16);
    o.y = (uint32_t)e2 | ((uint32_t)e3 << 16);
    *(uint2*)&orow[c] = o;
  }
}

// ---------------- fine-phase GEMM: C[M][N] = A[M][K](bf16) * Bt[N][K](bf16)^T -------
// BM=BN=256, BK=32, 8 waves (2Mx4N), wave tile 128x64 (32 MFMA/K-tile/wave).
// Ring of 4 buffers (128 KB). Two phases per K-tile, 16 MFMA each:
//   [vmcnt(8); barrier; P0: stage A-halves(k+3), ds_read A(8)+B(2), prio1 16MFMA prio0]
//   [barrier;           P1: stage B-halves(k+3), ds_read B(2),      prio1 16MFMA prio0]
// Wait math: tile j's 4 halves issued at (j-3).P0/P1 (gap 5-6 phases >> DMA latency).
// Before k.P0: outstanding = tiles {k,k+1,k+2}; vmcnt(8) retires exactly tile k.
// Tail: vmcnt(4) at k=nT-2, vmcnt(0) at k=nT-1. WAR: slot (k+3)&3 = (k-1)&3, reads
// done before this iter's opening barrier. Conflict-free swizzle (PMC 0): 16B-chunk
// phys = logical ^ ((row>>1)&3); DMA dest linear, global src pre-swizzled.
// EPI 0: +bias (cols<qlimit scaled) -> bf16; 1: +bias GELU -> bf16; 2: +bias+res -> f32
template <int EPI>
__global__ __launch_bounds__(512, 2) void gemmf(const u16* __restrict__ A,
                                                const u16* __restrict__ Bt,
                                                const float* __restrict__ bias,
                                                const float* res, void* Cout,
                                                int Ndim, int K, float qscale,
                                                int qlimit, int gn) {
  __shared__ __align__(16) u16 lds[4][16384];  // slot: A 16KB + B 16KB
  const int tid = threadIdx.x, lane = tid & 63, wid = tid >> 6;
  const int wm = wid >> 2, wn = wid & 3;

  const int wg = blockIdx.x;
  const int swz = (wg & 7) * ((int)gridDim.x >> 3) + (wg >> 3);
  const int mblk = swz / gn, nb = swz - mblk * gn;
  const int m0 = mblk << 8, n0 = nb << 8;

  // staging: thread t -> row t>>2, phys chunk t&3, global sub-chunk (t&3)^((t>>3)&3)
  const int srow = tid >> 2;
  const int gsub = (tid & 3) ^ ((tid >> 3) & 3);
  const u16* Ag = A + (size_t)(m0 + srow) * K + gsub * 8;
  const u16* Bg = Bt + (size_t)(n0 + srow) * K + gsub * 8;
  const size_t rstep = (size_t)128 * K;
  char* lb = (char*)&lds[0][0];

  // fragment reads: row r, phys chunk g^((r>>1)&3)
  const int rrow = lane & 15, g = lane >> 4;
  const int xg = g ^ ((rrow >> 1) & 3);
  const int aoff = (wm * 128 + rrow) * 64 + xg * 16;           // + mf*1024
  const int boff = 16384 + (wn * 64 + rrow) * 64 + xg * 16;    // + nf*1024

  const f32x4 fzero = {0.f, 0.f, 0.f, 0.f};
  f32x4 acc[8][4];
#pragma unroll
  for (int i = 0; i < 8; ++i)
#pragma unroll
    for (int j = 0; j < 4; ++j) acc[i][j] = fzero;

#define STGA(tt) do { char* d_ = lb + ((tt) & 3) * 32768; \
    GLD16(Ag + (size_t)(tt) * 32, d_ + tid * 16); \
    GLD16(Ag + rstep + (size_t)(tt) * 32, d_ + 8192 + tid * 16); } while (0)
#define STGB(tt) do { char* d_ = lb + ((tt) & 3) * 32768; \
    GLD16(Bg + (size_t)(tt) * 32, d_ + 16384 + tid * 16); \
    GLD16(Bg + rstep + (size_t)(tt) * 32, d_ + 24576 + tid * 16); } while (0)

  const int nT = K >> 5;
  STGA(0); STGB(0);
  STGA(1); STGB(1);
  STGA(2); STGB(2);

  for (int k = 0; k < nT; ++k) {
    if (k < nT - 2) { WAITVM(8); }
    else if (k == nT - 2) { WAITVM(4); }
    else { WAITVM(0); }
    BARRIER();
    const char* sb = lb + (k & 3) * 32768;
    const bool st = (k + 3 < nT);
    // ---- phase 0: stage A(k+3); read A frags + B n0-1; C[:, n0-1]
    if (st) STGA(k + 3);
    bf16x8 a0 = *(const bf16x8*)(sb + aoff + 0 * 1024);
    bf16x8 a1 = *(const bf16x8*)(sb + aoff + 1 * 1024);
    bf16x8 a2 = *(const bf16x8*)(sb + aoff + 2 * 1024);
    bf16x8 a3 = *(const bf16x8*)(sb + aoff + 3 * 1024);
    bf16x8 a4 = *(const bf16x8*)(sb + aoff + 4 * 1024);
    bf16x8 a5 = *(const bf16x8*)(sb + aoff + 5 * 1024);
    bf16x8 a6 = *(const bf16x8*)(sb + aoff + 6 * 1024);
    bf16x8 a7 = *(const bf16x8*)(sb + aoff + 7 * 1024);
    bf16x8 b0 = *(const bf16x8*)(sb + boff + 0 * 1024);
    bf16x8 b1 = *(const bf16x8*)(sb + boff + 1 * 1024);
    __builtin_amdgcn_s_setprio(1);
    acc[0][0] = MM(a0, b0, acc[0][0]); acc[1][0] = MM(a1, b0, acc[1][0]);
    acc[2][0] = MM(a2, b0, acc[2][0]); acc[3][0] = MM(a3, b0, acc[3][0]);
    acc[4][0] = MM(a4, b0, acc[4][0]); acc[5][0] = MM(a5, b0, acc[5][0]);
    acc[6][0] = MM(a6, b0, acc[6][0]); acc[7][0] = MM(a7, b0, acc[7][0]);
    acc[0][1] = MM(a0, b1, acc[0][1]); acc[1][1] = MM(a1, b1, acc[1][1]);
    acc[2][1] = MM(a2, b1, acc[2][1]); acc[3][1] = MM(a3, b1, acc[3][1]);
    acc[4][1] = MM(a4, b1, acc[4][1]); acc[5][1] = MM(a5, b1, acc[5][1]);
    acc[6][1] = MM(a6, b1, acc[6][1]); acc[7][1] = MM(a7, b1, acc[7][1]);
    __builtin_amdgcn_s_setprio(0);
    BARRIER();
    // ---- phase 1: stage B(k+3); read B n2-3; C[:, n2-3]
    if (st) STGB(k + 3);
    bf16x8 b2 = *(const bf16x8*)(sb + boff + 2 * 1024);
    bf16x8 b3 = *(const bf16x8*)(sb + boff + 3 * 1024);
    __builtin_amdgcn_s_setprio(1);
    acc[0][2] = MM(a0, b2, acc[0][2]); acc[1][2] = MM(a1, b2, acc[1][2]);
    acc[2][2] = MM(a2, b2, acc[2][2]); acc[3][2] = MM(a3, b2, acc[3][2]);
    acc[4][2] = MM(a4, b2, acc[4][2]); acc[5][2] = MM(a5, b2, acc[5][2]);
    acc[6][2] = MM(a6, b2, acc[6][2]); acc[7][2] = MM(a7, b2, acc[7][2]);
    acc[0][3] = MM(a0, b3, acc[0][3]); acc[1][3] = MM(a1, b3, acc[1][3]);
    acc[2][3] = MM(a2, b3, acc[2][3]); acc[3][3] = MM(a3, b3, acc[3][3]);
    acc[4][3] = MM(a4, b3, acc[4][3]); acc[5][3] = MM(a5, b3, acc[5][3]);
    acc[6][3] = MM(a6, b3, acc[6][3]); acc[7][3] = MM(a7, b3, acc[7][3]);
    __builtin_amdgcn_s_setprio(0);
  }
#undef STGA
#undef STGB

  const int g4 = (lane >> 4) << 2;
#pragma unroll
  for (int nf = 0; nf < 4; ++nf) {
    const int col = n0 + wn * 64 + nf * 16 + rrow;
    const float bvb = bias[col];
    const float csf = (EPI == 0 && col < qlimit) ? qscale : 1.0f;
#pragma unroll
    for (int mf = 0; mf < 8; ++mf) {
#pragma unroll
      for (int r = 0; r < 4; ++r) {
        const int row = m0 + wm * 128 + mf * 16 + g4 + r;
        float v = acc[mf][nf][r] + bvb;
        if (EPI == 0) v *= csf;
        if (EPI == 1) v = 0.5f * v * (1.0f + erff(v * 0.70710678118654752f));
        if (EPI == 2) {
          v += res[(size_t)row * Ndim + col];
          ((float*)Cout)[(size_t)row * Ndim + col] = v;
        } else {
          ((u16*)Cout)[(size_t)row * Ndim + col] = f2bf(v);
        }
      }
    }
  }
}

// ---------------- V transpose: qkv V block -> vt[bh][d][n] bf16 --------------------
__global__ __launch_bounds__(256) void vtrans(const u16* __restrict__ qkv,
                                              u16* __restrict__ vt) {
  const int bh = blockIdx.y, b = bh >> 4, h = bh & 15;
  const int n0 = blockIdx.x << 6;
  __shared__ __align__(16) u16 tile[64][72];
  const int t = threadIdx.x, r = t >> 2, c = t & 3;
  const u16* src = qkv + (size_t)((b << 10) + n0 + r) * 3072 + 2048 + (h << 6);
#pragma unroll
  for (int p = 0; p < 2; ++p)
    *(uint4*)&tile[r][(c * 2 + p) * 8] = *(const uint4*)(src + (c * 2 + p) * 8);
  __syncthreads();
  u16* dst = vt + (size_t)((bh << 6) + r) * 1024 + n0;
#pragma unroll
  for (int p = 0; p < 2; ++p) {
    u16 o[8];
#pragma unroll
    for (int j = 0; j < 8; ++j) o[j] = tile[(c * 2 + p) * 8 + j][r];
    uint4 w;
    w.x = (uint32_t)o[0] | ((uint32_t)o[1] << 16);
    w.y = (uint32_t)o[2] | ((uint32_t)o[3] << 16);
    w.z = (uint32_t)o[4] | ((uint32_t)o[5] << 16);
    w.w = (uint32_t)o[6] | ((uint32_t)o[7] << 16);
    *(uint4*)&dst[(c * 2 + p) * 8] = w;
  }
}

// ---------------- flash attention (no-max softmax, swapped QK^T) -------------------
__global__ __launch_bounds__(256) void attn64(const u16* __restrict__ qkv,
                                              const u16* __restrict__ vt,
                                              u16* __restrict__ aout) {
  const int bh = blockIdx.y, b = bh >> 4, h = bh & 15;
  const int q0 = blockIdx.x << 6;
  const int tid = threadIdx.x, lane = tid & 63, wid = tid >> 6;
  __shared__ __align__(16) u16 kl[4096];
  __shared__ __align__(16) u16 vl[4096];
  __shared__ __align__(16) u16 pl[4][1152];  // [wave][16 q][72]: P rows, k-major

  const int rrow = lane & 15;
  const int g = lane >> 4;
  const u16* qrow = qkv + (size_t)((b << 10) + q0 + (wid << 4) + rrow) * 3072 + (h << 6);
  bf16x8 qf0 = *(const bf16x8*)(qrow + (g << 3));
  bf16x8 qf1 = *(const bf16x8*)(qrow + 32 + (g << 3));

  const int sr = lane >> 3;
  const int lc = (lane & 7) ^ sr;
  const u16* kbase = qkv + (size_t)(b << 10) * 3072 + 1024 + (h << 6) +
                     (size_t)(16 * wid + sr) * 3072 + lc * 8;
  const u16* vbase = vt + (size_t)(bh << 6) * 1024 + (size_t)(16 * wid + sr) * 1024 + lc * 8;

  const f32x4 fzero = {0.f, 0.f, 0.f, 0.f};
  f32x4 oacc[4];
#pragma unroll
  for (int i = 0; i < 4; ++i) oacc[i] = fzero;
  f32x4 lacc = fzero;
  const int rcb = lane & 7;
  u16* plw = &pl[wid][0];

  for (int t = 0; t < 16; ++t) {
    const int kt0 = t << 6;
    GLD16(kbase + (size_t)kt0 * 3072, &kl[(2 * wid + 0) * 512]);
    GLD16(kbase + (size_t)kt0 * 3072 + 8 * 3072, &kl[(2 * wid + 1) * 512]);
    GLD16(vbase + kt0, &vl[(2 * wid + 0) * 512]);
    GLD16(vbase + kt0 + 8 * 1024, &vl[(2 * wid + 1) * 512]);
    __syncthreads();

    f32x4 s4[4];
#pragma unroll
    for (int i = 0; i < 4; ++i) s4[i] = fzero;
#pragma unroll
    for (int nf = 0; nf < 4; ++nf) {
      bf16x8 k0 = *(const bf16x8*)((const char*)kl + (nf * 16 + rrow) * 128 +
                                   ((g + 0) ^ rcb) * 16);
      bf16x8 k1 = *(const bf16x8*)((const char*)kl + (nf * 16 + rrow) * 128 +
                                   ((g + 4) ^ rcb) * 16);
      s4[nf] = __builtin_amdgcn_mfma_f32_16x16x32_bf16(k0, qf0, s4[nf], 0, 0, 0);
      s4[nf] = __builtin_amdgcn_mfma_f32_16x16x32_bf16(k1, qf1, s4[nf], 0, 0, 0);
    }

#pragma unroll
    for (int nf = 0; nf < 4; ++nf) {
      float p0 = exp2f(s4[nf][0]);
      float p1 = exp2f(s4[nf][1]);
      float p2 = exp2f(s4[nf][2]);
      float p3 = exp2f(s4[nf][3]);
      f32x4 pv = {p0, p1, p2, p3};
      lacc += pv;
      uint32_t a0 = __builtin_bit_cast(uint32_t, p0) + 0x8000u;
      uint32_t a1 = __builtin_bit_cast(uint32_t, p1) + 0x8000u;
      uint32_t a2 = __builtin_bit_cast(uint32_t, p2) + 0x8000u;
      uint32_t a3 = __builtin_bit_cast(uint32_t, p3) + 0x8000u;
      uint2 w;
      w.x = __builtin_amdgcn_perm(a1, a0, 0x07060302);
      w.y = __builtin_amdgcn_perm(a3, a2, 0x07060302);
      *(uint2*)(plw + rrow * 72 + nf * 16 + (g << 2)) = w;
    }

    bf16x8 pf0 = *(const bf16x8*)((const char*)plw + rrow * 144 + (g << 4));
    bf16x8 pf1 = *(const bf16x8*)((const char*)plw + rrow * 144 + (g << 4) + 64);
#pragma unroll
    for (int nf = 0; nf < 4; ++nf) {
      bf16x8 v0 = *(const bf16x8*)((const char*)vl + (nf * 16 + rrow) * 128 +
                                   ((g + 0) ^ rcb) * 16);
      bf16x8 v1 = *(const bf16x8*)((const char*)vl + (nf * 16 + rrow) * 128 +
                                   ((g + 4) ^ rcb) * 16);
      oacc[nf] = __builtin_amdgcn_mfma_f32_16x16x32_bf16(pf0, v0, oacc[nf], 0, 0, 0);
      oacc[nf] = __builtin_amdgcn_mfma_f32_16x16x32_bf16(pf1, v1, oacc[nf], 0, 0, 0);
    }
    __syncthreads();
  }

  float lsum = lacc[0] + lacc[1] + lacc[2] + lacc[3];
  lsum += __shfl_xor(lsum, 16);
  lsum += __shfl_xor(lsum, 32);
  const float inv = 1.0f / lsum;
  float invq[4];
#pragma unroll
  for (int r = 0; r < 4; ++r) {
    int bi = __builtin_amdgcn_ds_bpermute(((g << 2) + r) << 2,
                                          __builtin_bit_cast(int, inv));
    invq[r] = __builtin_bit_cast(float, bi);
  }
  u16* ob = aout + (size_t)((b << 10) + q0 + (wid << 4)) * 1024 + (h << 6);
#pragma unroll
  for (int nf = 0; nf < 4; ++nf)
#pragma unroll
    for (int r = 0; r < 4; ++r)
      ob[(size_t)(g * 4 + r) * 1024 + nf * 16 + rrow] = f2bf(oacc[nf][r] * invq[r]);
}

// ---------------- launcher ---------------------------------------------------------
extern "C" void kernel_launch(void* const* d_in, const int* in_sizes, int n_in,
                              void* d_out, int out_size, void* d_ws, size_t ws_size,
                              hipStream_t stream) {
  const float* x = (const float*)d_in[0];
  const float* ln1_g = (const float*)d_in[1];
  const float* ln1_b = (const float*)d_in[2];
  const float* w_qkv = (const float*)d_in[3];
  const float* b_qkv = (const float*)d_in[4];
  const float* w_o = (const float*)d_in[5];
  const float* b_o = (const float*)d_in[6];
  const float* ln2_g = (const float*)d_in[7];
  const float* ln2_b = (const float*)d_in[8];
  const float* w_fc1 = (const float*)d_in[9];
  const float* b_fc1 = (const float*)d_in[10];
  const float* w_fc2 = (const float*)d_in[11];
  const float* b_fc2 = (const float*)d_in[12];
  float* out = (float*)d_out;

  char* w = (char*)d_ws;
  u16* wqkvT = (u16*)w; w += (size_t)3072 * 1024 * 2;
  u16* woT   = (u16*)w; w += (size_t)1024 * 1024 * 2;
  u16* wfc1T = (u16*)w; w += (size_t)4096 * 1024 * 2;
  u16* wfc2T = (u16*)w; w += (size_t)1024 * 4096 * 2;
  u16* xn    = (u16*)w; w += (size_t)8192 * 1024 * 2;
  u16* qkvb  = (u16*)w; w += (size_t)8192 * 3072 * 2;
  u16* vtb   = (u16*)w; w += (size_t)128 * 64 * 1024 * 2;
  u16* attnb = (u16*)w; w += (size_t)8192 * 1024 * 2;
  u16* hbuf  = qkvb;  // overlay: qkv+vt dead when h is produced

  const float QS = 0.18033688011112042f;  // 0.125 * log2(e)

  wtrans<<<dim3(48, 16), 256, 0, stream>>>(w_qkv, wqkvT, 1024, 3072);
  wtrans<<<dim3(16, 16), 256, 0, stream>>>(w_o, woT, 1024, 1024);
  wtrans<<<dim3(64, 16), 256, 0, stream>>>(w_fc1, wfc1T, 1024, 4096);
  wtrans<<<dim3(16, 64), 256, 0, stream>>>(w_fc2, wfc2T, 4096, 1024);

  lnorm<<<2048, 256, 0, stream>>>(x, ln1_g, ln1_b, xn);
  gemmf<0><<<384, 512, 0, stream>>>(xn, wqkvT, b_qkv, nullptr, qkvb, 3072, 1024, QS, 1024, 12);
  vtrans<<<dim3(16, 128), 256, 0, stream>>>(qkvb, vtb);
  attn64<<<dim3(16, 128), 256, 0, stream>>>(qkvb, vtb, attnb);
  gemmf<2><<<128, 512, 0, stream>>>(attnb, woT, b_o, x, out, 1024, 1024, 1.f, 0, 4);
  lnorm<<<2048, 256, 0, stream>>>(out, ln2_g, ln2_b, xn);
  gemmf<1><<<512, 512, 0, stream>>>(xn, wfc1T, b_fc1, nullptr, hbuf, 4096, 1024, 1.f, 0, 16);
  gemmf<2><<<128, 512, 0, stream>>>(hbuf, wfc2T, b_fc2, out, out, 1024, 4096, 1.f, 0, 4);
}

// Round 8
// 414.119 us; speedup vs baseline: 1.1604x; 1.1523x over previous
//
#include <hip/hip_runtime.h>
#include <stdint.h>

typedef unsigned short u16;
typedef __bf16 bf16x8 __attribute__((ext_vector_type(8)));
typedef float f32x4 __attribute__((ext_vector_type(4)));

#define GLD16(gp, lp) __builtin_amdgcn_global_load_lds( \
    (__attribute__((address_space(1))) void*)(uintptr_t)(gp), \
    (__attribute__((address_space(3))) void*)(uintptr_t)(lp), 16, 0, 0)

#define MM(a, b, c) __builtin_amdgcn_mfma_f32_16x16x32_bf16(a, b, c, 0, 0, 0)

__device__ __forceinline__ u16 f2bf(float f) {
  uint32_t u = __builtin_bit_cast(uint32_t, f);
  u += 0x7FFFu + ((u >> 16) & 1u);
  return (u16)(u >> 16);
}

// ---------------- weight transpose + convert: w[K][N] f32 -> wt[N][K] bf16 ----------
__global__ __launch_bounds__(256) void wtrans(const float* __restrict__ w,
                                              u16* __restrict__ wt, int K, int Nn) {
  __shared__ float tile[64][68];
  const int c0 = blockIdx.x << 6, r0 = blockIdx.y << 6;
  const int t = threadIdx.x, tr = t >> 2, tc = t & 3;
#pragma unroll
  for (int p = 0; p < 4; ++p) {
    float4 v = *(const float4*)&w[(size_t)(r0 + tr) * Nn + c0 + tc * 4 + p * 16];
    tile[tr][tc * 4 + p * 16 + 0] = v.x;
    tile[tr][tc * 4 + p * 16 + 1] = v.y;
    tile[tr][tc * 4 + p * 16 + 2] = v.z;
    tile[tr][tc * 4 + p * 16 + 3] = v.w;
  }
  __syncthreads();
#pragma unroll
  for (int p = 0; p < 4; ++p) {
    u16 e0 = f2bf(tile[tc * 4 + p * 16 + 0][tr]);
    u16 e1 = f2bf(tile[tc * 4 + p * 16 + 1][tr]);
    u16 e2 = f2bf(tile[tc * 4 + p * 16 + 2][tr]);
    u16 e3 = f2bf(tile[tc * 4 + p * 16 + 3][tr]);
    uint2 o;
    o.x = (uint32_t)e0 | ((uint32_t)e1 << 16);
    o.y = (uint32_t)e2 | ((uint32_t)e3 << 16);
    *(uint2*)&wt[(size_t)(c0 + tr) * K + r0 + tc * 4 + p * 16] = o;
  }
}

// ---------------- LayerNorm: x[M][1024] f32 -> out bf16 ----------------------------
__global__ __launch_bounds__(256) void lnorm(const float* x, const float* __restrict__ g,
                                             const float* __restrict__ bta,
                                             u16* __restrict__ out) {
  const int lane = threadIdx.x & 63, wid = threadIdx.x >> 6;
  const size_t token = (size_t)blockIdx.x * 4 + wid;
  const float* row = x + token * 1024;
  float v[16];
#pragma unroll
  for (int i = 0; i < 4; ++i) {
    float4 f = *(const float4*)&row[(lane + i * 64) * 4];
    v[i * 4 + 0] = f.x; v[i * 4 + 1] = f.y; v[i * 4 + 2] = f.z; v[i * 4 + 3] = f.w;
  }
  float s = 0.f, s2 = 0.f;
#pragma unroll
  for (int i = 0; i < 16; ++i) { s += v[i]; s2 += v[i] * v[i]; }
  for (int off = 1; off < 64; off <<= 1) {
    s += __shfl_xor(s, off);
    s2 += __shfl_xor(s2, off);
  }
  const float mu = s * (1.0f / 1024.0f);
  const float var = s2 * (1.0f / 1024.0f) - mu * mu;
  const float rstd = rsqrtf(var + 1e-6f);
  u16* orow = out + token * 1024;
#pragma unroll
  for (int i = 0; i < 4; ++i) {
    const int c = (lane + i * 64) * 4;
    float4 gv = *(const float4*)&g[c];
    float4 bv = *(const float4*)&bta[c];
    u16 e0 = f2bf((v[i * 4 + 0] - mu) * rstd * gv.x + bv.x);
    u16 e1 = f2bf((v[i * 4 + 1] - mu) * rstd * gv.y + bv.y);
    u16 e2 = f2bf((v[i * 4 + 2] - mu) * rstd * gv.z + bv.z);
    u16 e3 = f2bf((v[i * 4 + 3] - mu) * rstd * gv.w + bv.w);
    uint2 o;
    o.x = (uint32_t)e0 | ((uint32_t)e1 << 16);
    o.y = (uint32_t)e2 | ((uint32_t)e3 << 16);
    *(uint2*)&orow[c] = o;
  }
}

// ---------------- m97-config GEMM: C[M][N] = A[M][K](bf16) * Bt[N][K](bf16)^T -------
// 128x128 tile, 4 waves (2x2, wave-tile 64x64), 2-slot dbuf LDS (32 KB) -> high
// blocks/CU (DMA fill rate scales with resident waves -- R2..R7 evidence).
// Loop: {stage next tile (4 GLD16) ; ds_read 8 frags ; 16 MFMA ; __syncthreads}.
// Conflict-free chunk swizzle (PMC-verified 0): phys 16B-chunk = logical ^ ((row>>1)&3);
// DMA dest linear, global source pre-swizzled. Bijective XCD block swizzle.
// EPI 0: +bias (cols<qlimit scaled) -> bf16; 1: +bias GELU -> bf16; 2: +bias+res -> f32
template <int EPI>
__global__ __launch_bounds__(256, 4) void g97(const u16* __restrict__ A,
                                              const u16* __restrict__ Bt,
                                              const float* __restrict__ bias,
                                              const float* res, void* Cout,
                                              int Ndim, int K, float qscale,
                                              int qlimit, int gn) {
  __shared__ __align__(16) u16 lds[2][8192];  // slot: A 8KB + B 8KB
  const int tid = threadIdx.x, lane = tid & 63, wid = tid >> 6;
  const int wm = wid & 1, wn = wid >> 1;

  const int wg = blockIdx.x;
  const int swz = (wg & 7) * ((int)gridDim.x >> 3) + (wg >> 3);
  const int mblk = swz / gn, nb = swz - mblk * gn;
  const int m0 = mblk << 7, n0 = nb << 7;

  // staging: thread t -> row t>>2 (64 rows/GLD), phys chunk t&3,
  // global sub-chunk (t&3)^((t>>3)&3)
  const int srow = tid >> 2;
  const int gsub = (tid & 3) ^ ((tid >> 3) & 3);
  const u16* Ag = A + (size_t)(m0 + srow) * K + gsub * 8;
  const u16* Bg = Bt + (size_t)(n0 + srow) * K + gsub * 8;
  const size_t rstep = (size_t)64 * K;
  char* lb = (char*)&lds[0][0];

  // fragment reads: row r, phys chunk g^((r>>1)&3)
  const int rrow = lane & 15, g = lane >> 4;
  const int xg = g ^ ((rrow >> 1) & 3);
  const int aoff = (wm * 64 + rrow) * 64 + xg * 16;          // + mf*1024
  const int boff = 8192 + (wn * 64 + rrow) * 64 + xg * 16;   // + nf*1024

  const f32x4 fzero = {0.f, 0.f, 0.f, 0.f};
  f32x4 acc[4][4];
#pragma unroll
  for (int i = 0; i < 4; ++i)
#pragma unroll
    for (int j = 0; j < 4; ++j) acc[i][j] = fzero;

#define STG(kt, s) do { \
    char* d_ = lb + (s) * 16384; \
    GLD16(Ag + (size_t)(kt) * 32, d_ + tid * 16); \
    GLD16(Ag + rstep + (size_t)(kt) * 32, d_ + 4096 + tid * 16); \
    GLD16(Bg + (size_t)(kt) * 32, d_ + 8192 + tid * 16); \
    GLD16(Bg + rstep + (size_t)(kt) * 32, d_ + 12288 + tid * 16); \
  } while (0)

  const int nk = K >> 5;
  STG(0, 0);
  __syncthreads();
  for (int kt = 0; kt < nk; ++kt) {
    if (kt + 1 < nk) STG(kt + 1, (kt + 1) & 1);
    const char* sb = lb + (kt & 1) * 16384;
    bf16x8 af[4], bfr[4];
#pragma unroll
    for (int mf = 0; mf < 4; ++mf)
      af[mf] = *(const bf16x8*)(sb + aoff + mf * 1024);
#pragma unroll
    for (int nf = 0; nf < 4; ++nf)
      bfr[nf] = *(const bf16x8*)(sb + boff + nf * 1024);
#pragma unroll
    for (int mf = 0; mf < 4; ++mf)
#pragma unroll
      for (int nf = 0; nf < 4; ++nf)
        acc[mf][nf] = MM(af[mf], bfr[nf], acc[mf][nf]);
    __syncthreads();
  }
#undef STG

  const int g4 = (lane >> 4) << 2;
#pragma unroll
  for (int nf = 0; nf < 4; ++nf) {
    const int col = n0 + wn * 64 + nf * 16 + rrow;
    const float bvb = bias[col];
    const float csf = (EPI == 0 && col < qlimit) ? qscale : 1.0f;
#pragma unroll
    for (int mf = 0; mf < 4; ++mf) {
#pragma unroll
      for (int r = 0; r < 4; ++r) {
        const int row = m0 + wm * 64 + mf * 16 + g4 + r;
        float v = acc[mf][nf][r] + bvb;
        if (EPI == 0) v *= csf;
        if (EPI == 1) v = 0.5f * v * (1.0f + erff(v * 0.70710678118654752f));
        if (EPI == 2) {
          v += res[(size_t)row * Ndim + col];
          ((float*)Cout)[(size_t)row * Ndim + col] = v;
        } else {
          ((u16*)Cout)[(size_t)row * Ndim + col] = f2bf(v);
        }
      }
    }
  }
}

// ---------------- V transpose: qkv V block -> vt[bh][d][n] bf16 --------------------
__global__ __launch_bounds__(256) void vtrans(const u16* __restrict__ qkv,
                                              u16* __restrict__ vt) {
  const int bh = blockIdx.y, b = bh >> 4, h = bh & 15;
  const int n0 = blockIdx.x << 6;
  __shared__ __align__(16) u16 tile[64][72];
  const int t = threadIdx.x, r = t >> 2, c = t & 3;
  const u16* src = qkv + (size_t)((b << 10) + n0 + r) * 3072 + 2048 + (h << 6);
#pragma unroll
  for (int p = 0; p < 2; ++p)
    *(uint4*)&tile[r][(c * 2 + p) * 8] = *(const uint4*)(src + (c * 2 + p) * 8);
  __syncthreads();
  u16* dst = vt + (size_t)((bh << 6) + r) * 1024 + n0;
#pragma unroll
  for (int p = 0; p < 2; ++p) {
    u16 o[8];
#pragma unroll
    for (int j = 0; j < 8; ++j) o[j] = tile[(c * 2 + p) * 8 + j][r];
    uint4 w;
    w.x = (uint32_t)o[0] | ((uint32_t)o[1] << 16);
    w.y = (uint32_t)o[2] | ((uint32_t)o[3] << 16);
    w.z = (uint32_t)o[4] | ((uint32_t)o[5] << 16);
    w.w = (uint32_t)o[6] | ((uint32_t)o[7] << 16);
    *(uint4*)&dst[(c * 2 + p) * 8] = w;
  }
}

// ---------------- flash attention (no-max softmax, swapped QK^T) -------------------
__global__ __launch_bounds__(256) void attn64(const u16* __restrict__ qkv,
                                              const u16* __restrict__ vt,
                                              u16* __restrict__ aout) {
  const int bh = blockIdx.y, b = bh >> 4, h = bh & 15;
  const int q0 = blockIdx.x << 6;
  const int tid = threadIdx.x, lane = tid & 63, wid = tid >> 6;
  __shared__ __align__(16) u16 kl[4096];
  __shared__ __align__(16) u16 vl[4096];
  __shared__ __align__(16) u16 pl[4][1152];  // [wave][16 q][72]: P rows, k-major

  const int rrow = lane & 15;
  const int g = lane >> 4;
  const u16* qrow = qkv + (size_t)((b << 10) + q0 + (wid << 4) + rrow) * 3072 + (h << 6);
  bf16x8 qf0 = *(const bf16x8*)(qrow + (g << 3));
  bf16x8 qf1 = *(const bf16x8*)(qrow + 32 + (g << 3));

  const int sr = lane >> 3;
  const int lc = (lane & 7) ^ sr;
  const u16* kbase = qkv + (size_t)(b << 10) * 3072 + 1024 + (h << 6) +
                     (size_t)(16 * wid + sr) * 3072 + lc * 8;
  const u16* vbase = vt + (size_t)(bh << 6) * 1024 + (size_t)(16 * wid + sr) * 1024 + lc * 8;

  const f32x4 fzero = {0.f, 0.f, 0.f, 0.f};
  f32x4 oacc[4];
#pragma unroll
  for (int i = 0; i < 4; ++i) oacc[i] = fzero;
  f32x4 lacc = fzero;
  const int rcb = lane & 7;
  u16* plw = &pl[wid][0];

  for (int t = 0; t < 16; ++t) {
    const int kt0 = t << 6;
    GLD16(kbase + (size_t)kt0 * 3072, &kl[(2 * wid + 0) * 512]);
    GLD16(kbase + (size_t)kt0 * 3072 + 8 * 3072, &kl[(2 * wid + 1) * 512]);
    GLD16(vbase + kt0, &vl[(2 * wid + 0) * 512]);
    GLD16(vbase + kt0 + 8 * 1024, &vl[(2 * wid + 1) * 512]);
    __syncthreads();

    f32x4 s4[4];
#pragma unroll
    for (int i = 0; i < 4; ++i) s4[i] = fzero;
#pragma unroll
    for (int nf = 0; nf < 4; ++nf) {
      bf16x8 k0 = *(const bf16x8*)((const char*)kl + (nf * 16 + rrow) * 128 +
                                   ((g + 0) ^ rcb) * 16);
      bf16x8 k1 = *(const bf16x8*)((const char*)kl + (nf * 16 + rrow) * 128 +
                                   ((g + 4) ^ rcb) * 16);
      s4[nf] = __builtin_amdgcn_mfma_f32_16x16x32_bf16(k0, qf0, s4[nf], 0, 0, 0);
      s4[nf] = __builtin_amdgcn_mfma_f32_16x16x32_bf16(k1, qf1, s4[nf], 0, 0, 0);
    }

#pragma unroll
    for (int nf = 0; nf < 4; ++nf) {
      float p0 = exp2f(s4[nf][0]);
      float p1 = exp2f(s4[nf][1]);
      float p2 = exp2f(s4[nf][2]);
      float p3 = exp2f(s4[nf][3]);
      f32x4 pv = {p0, p1, p2, p3};
      lacc += pv;
      uint32_t a0 = __builtin_bit_cast(uint32_t, p0) + 0x8000u;
      uint32_t a1 = __builtin_bit_cast(uint32_t, p1) + 0x8000u;
      uint32_t a2 = __builtin_bit_cast(uint32_t, p2) + 0x8000u;
      uint32_t a3 = __builtin_bit_cast(uint32_t, p3) + 0x8000u;
      uint2 w;
      w.x = __builtin_amdgcn_perm(a1, a0, 0x07060302);
      w.y = __builtin_amdgcn_perm(a3, a2, 0x07060302);
      *(uint2*)(plw + rrow * 72 + nf * 16 + (g << 2)) = w;
    }

    bf16x8 pf0 = *(const bf16x8*)((const char*)plw + rrow * 144 + (g << 4));
    bf16x8 pf1 = *(const bf16x8*)((const char*)plw + rrow * 144 + (g << 4) + 64);
#pragma unroll
    for (int nf = 0; nf < 4; ++nf) {
      bf16x8 v0 = *(const bf16x8*)((const char*)vl + (nf * 16 + rrow) * 128 +
                                   ((g + 0) ^ rcb) * 16);
      bf16x8 v1 = *(const bf16x8*)((const char*)vl + (nf * 16 + rrow) * 128 +
                                   ((g + 4) ^ rcb) * 16);
      oacc[nf] = __builtin_amdgcn_mfma_f32_16x16x32_bf16(pf0, v0, oacc[nf], 0, 0, 0);
      oacc[nf] = __builtin_amdgcn_mfma_f32_16x16x32_bf16(pf1, v1, oacc[nf], 0, 0, 0);
    }
    __syncthreads();
  }

  float lsum = lacc[0] + lacc[1] + lacc[2] + lacc[3];
  lsum += __shfl_xor(lsum, 16);
  lsum += __shfl_xor(lsum, 32);
  const float inv = 1.0f / lsum;
  float invq[4];
#pragma unroll
  for (int r = 0; r < 4; ++r) {
    int bi = __builtin_amdgcn_ds_bpermute(((g << 2) + r) << 2,
                                          __builtin_bit_cast(int, inv));
    invq[r] = __builtin_bit_cast(float, bi);
  }
  u16* ob = aout + (size_t)((b << 10) + q0 + (wid << 4)) * 1024 + (h << 6);
#pragma unroll
  for (int nf = 0; nf < 4; ++nf)
#pragma unroll
    for (int r = 0; r < 4; ++r)
      ob[(size_t)(g * 4 + r) * 1024 + nf * 16 + rrow] = f2bf(oacc[nf][r] * invq[r]);
}

// ---------------- launcher ---------------------------------------------------------
extern "C" void kernel_launch(void* const* d_in, const int* in_sizes, int n_in,
                              void* d_out, int out_size, void* d_ws, size_t ws_size,
                              hipStream_t stream) {
  const float* x = (const float*)d_in[0];
  const float* ln1_g = (const float*)d_in[1];
  const float* ln1_b = (const float*)d_in[2];
  const float* w_qkv = (const float*)d_in[3];
  const float* b_qkv = (const float*)d_in[4];
  const float* w_o = (const float*)d_in[5];
  const float* b_o = (const float*)d_in[6];
  const float* ln2_g = (const float*)d_in[7];
  const float* ln2_b = (const float*)d_in[8];
  const float* w_fc1 = (const float*)d_in[9];
  const float* b_fc1 = (const float*)d_in[10];
  const float* w_fc2 = (const float*)d_in[11];
  const float* b_fc2 = (const float*)d_in[12];
  float* out = (float*)d_out;

  char* w = (char*)d_ws;
  u16* wqkvT = (u16*)w; w += (size_t)3072 * 1024 * 2;
  u16* woT   = (u16*)w; w += (size_t)1024 * 1024 * 2;
  u16* wfc1T = (u16*)w; w += (size_t)4096 * 1024 * 2;
  u16* wfc2T = (u16*)w; w += (size_t)1024 * 4096 * 2;
  u16* xn    = (u16*)w; w += (size_t)8192 * 1024 * 2;
  u16* qkvb  = (u16*)w; w += (size_t)8192 * 3072 * 2;
  u16* vtb   = (u16*)w; w += (size_t)128 * 64 * 1024 * 2;
  u16* attnb = (u16*)w; w += (size_t)8192 * 1024 * 2;
  u16* hbuf  = qkvb;  // overlay: qkv+vt dead when h is produced

  const float QS = 0.18033688011112042f;  // 0.125 * log2(e)

  wtrans<<<dim3(48, 16), 256, 0, stream>>>(w_qkv, wqkvT, 1024, 3072);
  wtrans<<<dim3(16, 16), 256, 0, stream>>>(w_o, woT, 1024, 1024);
  wtrans<<<dim3(64, 16), 256, 0, stream>>>(w_fc1, wfc1T, 1024, 4096);
  wtrans<<<dim3(16, 64), 256, 0, stream>>>(w_fc2, wfc2T, 4096, 1024);

  lnorm<<<2048, 256, 0, stream>>>(x, ln1_g, ln1_b, xn);
  g97<0><<<1536, 256, 0, stream>>>(xn, wqkvT, b_qkv, nullptr, qkvb, 3072, 1024, QS, 1024, 24);
  vtrans<<<dim3(16, 128), 256, 0, stream>>>(qkvb, vtb);
  attn64<<<dim3(16, 128), 256, 0, stream>>>(qkvb, vtb, attnb);
  g97<2><<<512, 256, 0, stream>>>(attnb, woT, b_o, x, out, 1024, 1024, 1.f, 0, 8);
  lnorm<<<2048, 256, 0, stream>>>(out, ln2_g, ln2_b, xn);
  g97<1><<<2048, 256, 0, stream>>>(xn, wfc1T, b_fc1, nullptr, hbuf, 4096, 1024, 1.f, 0, 32);
  g97<2><<<512, 256, 0, stream>>>(hbuf, wfc2T, b_fc2, out, out, 1024, 4096, 1.f, 0, 8);
}

// Round 9
// 408.633 us; speedup vs baseline: 1.1760x; 1.0134x over previous
//
#include <hip/hip_runtime.h>
#include <stdint.h>

typedef unsigned short u16;
typedef __bf16 bf16x8 __attribute__((ext_vector_type(8)));
typedef float f32x4 __attribute__((ext_vector_type(4)));

#define GLD16(gp, lp) __builtin_amdgcn_global_load_lds( \
    (__attribute__((address_space(1))) void*)(uintptr_t)(gp), \
    (__attribute__((address_space(3))) void*)(uintptr_t)(lp), 16, 0, 0)

#define MM(a, b, c) __builtin_amdgcn_mfma_f32_16x16x32_bf16(a, b, c, 0, 0, 0)

__device__ __forceinline__ u16 f2bf(float f) {
  uint32_t u = __builtin_bit_cast(uint32_t, f);
  u += 0x7FFFu + ((u >> 16) & 1u);
  return (u16)(u >> 16);
}

// ---------------- weight transpose + convert: w[K][N] f32 -> wt[N][K] bf16 ----------
__global__ __launch_bounds__(256) void wtrans(const float* __restrict__ w,
                                              u16* __restrict__ wt, int K, int Nn) {
  __shared__ float tile[64][68];
  const int c0 = blockIdx.x << 6, r0 = blockIdx.y << 6;
  const int t = threadIdx.x, tr = t >> 2, tc = t & 3;
#pragma unroll
  for (int p = 0; p < 4; ++p) {
    float4 v = *(const float4*)&w[(size_t)(r0 + tr) * Nn + c0 + tc * 4 + p * 16];
    tile[tr][tc * 4 + p * 16 + 0] = v.x;
    tile[tr][tc * 4 + p * 16 + 1] = v.y;
    tile[tr][tc * 4 + p * 16 + 2] = v.z;
    tile[tr][tc * 4 + p * 16 + 3] = v.w;
  }
  __syncthreads();
#pragma unroll
  for (int p = 0; p < 4; ++p) {
    u16 e0 = f2bf(tile[tc * 4 + p * 16 + 0][tr]);
    u16 e1 = f2bf(tile[tc * 4 + p * 16 + 1][tr]);
    u16 e2 = f2bf(tile[tc * 4 + p * 16 + 2][tr]);
    u16 e3 = f2bf(tile[tc * 4 + p * 16 + 3][tr]);
    uint2 o;
    o.x = (uint32_t)e0 | ((uint32_t)e1 << 16);
    o.y = (uint32_t)e2 | ((uint32_t)e3 << 16);
    *(uint2*)&wt[(size_t)(c0 + tr) * K + r0 + tc * 4 + p * 16] = o;
  }
}

// ---------------- LayerNorm: x[M][1024] f32 -> out bf16 ----------------------------
__global__ __launch_bounds__(256) void lnorm(const float* x, const float* __restrict__ g,
                                             const float* __restrict__ bta,
                                             u16* __restrict__ out) {
  const int lane = threadIdx.x & 63, wid = threadIdx.x >> 6;
  const size_t token = (size_t)blockIdx.x * 4 + wid;
  const float* row = x + token * 1024;
  float v[16];
#pragma unroll
  for (int i = 0; i < 4; ++i) {
    float4 f = *(const float4*)&row[(lane + i * 64) * 4];
    v[i * 4 + 0] = f.x; v[i * 4 + 1] = f.y; v[i * 4 + 2] = f.z; v[i * 4 + 3] = f.w;
  }
  float s = 0.f, s2 = 0.f;
#pragma unroll
  for (int i = 0; i < 16; ++i) { s += v[i]; s2 += v[i] * v[i]; }
  for (int off = 1; off < 64; off <<= 1) {
    s += __shfl_xor(s, off);
    s2 += __shfl_xor(s2, off);
  }
  const float mu = s * (1.0f / 1024.0f);
  const float var = s2 * (1.0f / 1024.0f) - mu * mu;
  const float rstd = rsqrtf(var + 1e-6f);
  u16* orow = out + token * 1024;
#pragma unroll
  for (int i = 0; i < 4; ++i) {
    const int c = (lane + i * 64) * 4;
    float4 gv = *(const float4*)&g[c];
    float4 bv = *(const float4*)&bta[c];
    u16 e0 = f2bf((v[i * 4 + 0] - mu) * rstd * gv.x + bv.x);
    u16 e1 = f2bf((v[i * 4 + 1] - mu) * rstd * gv.y + bv.y);
    u16 e2 = f2bf((v[i * 4 + 2] - mu) * rstd * gv.z + bv.z);
    u16 e3 = f2bf((v[i * 4 + 3] - mu) * rstd * gv.w + bv.w);
    uint2 o;
    o.x = (uint32_t)e0 | ((uint32_t)e1 << 16);
    o.y = (uint32_t)e2 | ((uint32_t)e3 << 16);
    *(uint2*)&orow[c] = o;
  }
}

// ---------------- BK=64 GEMM: C[M][N] = A[M][K](bf16) * Bt[N][K](bf16)^T ------------
// 128x128 tile, 4 waves (2x2, wave-tile 64x64), BK=64. 2-slot dbuf, slot = A 16KB +
// B 16KB -> 64 KB LDS, 2 blocks/CU. Prefetch of next K-step = 8 GLD16 = 32 KB in
// flight per block (x2 blocks = 64 KB/CU) -- ~4x R8's in-flight DMA, and half the
// barrier/loop overhead per staged byte.
// LDS row = 64 bf16 = 128 B = 8 chunks of 16B. Swizzle: phys chunk = logical ^
// (row&7) -> ds_read_b128 (lanes g=chunk c*4+g, rows rrow) hits each bank exactly
// 8x = conflict-free. DMA dest linear (base + t*16); global source pre-swizzled.
// c1 chunk offset = c0 byte offset XOR 64.
// EPI 0: +bias (cols<qlimit scaled) -> bf16; 1: +bias GELU -> bf16; 2: +bias+res -> f32
template <int EPI>
__global__ __launch_bounds__(256, 2) void g97(const u16* __restrict__ A,
                                              const u16* __restrict__ Bt,
                                              const float* __restrict__ bias,
                                              const float* res, void* Cout,
                                              int Ndim, int K, float qscale,
                                              int qlimit, int gn) {
  __shared__ __align__(16) u16 lds[2][16384];  // slot: A 16KB + B 16KB
  const int tid = threadIdx.x, lane = tid & 63, wid = tid >> 6;
  const int wm = wid & 1, wn = wid >> 1;

  const int wg = blockIdx.x;
  const int swz = (wg & 7) * ((int)gridDim.x >> 3) + (wg >> 3);
  const int mblk = swz / gn, nb = swz - mblk * gn;
  const int m0 = mblk << 7, n0 = nb << 7;

  // staging: thread t -> row srow = t>>3 (32 rows per GLD16), linear chunk t&7,
  // global sub-chunk = (t&7) ^ (srow&7)  (pre-swizzled source)
  const int srow = tid >> 3;
  const int schunk = (tid & 7) ^ (srow & 7);
  const u16* Ag = A + (size_t)(m0 + srow) * K + schunk * 8;
  const u16* Bg = Bt + (size_t)(n0 + srow) * K + schunk * 8;
  const size_t rstep = (size_t)32 * K;
  char* lb = (char*)&lds[0][0];

  // fragment reads: row r, phys chunk (c*4+g) ^ (r&7); c=1 base = c=0 base XOR 64
  const int rrow = lane & 15, g = lane >> 4;
  const int ph0 = (g ^ (rrow & 7)) * 16;  // byte offset of c=0 chunk in row
  const int aoff0 = (wm * 64 + rrow) * 128 + ph0;            // + mf*2048
  const int aoff1 = (wm * 64 + rrow) * 128 + (ph0 ^ 64);
  const int boff0 = 16384 + (wn * 64 + rrow) * 128 + ph0;    // + nf*2048
  const int boff1 = 16384 + (wn * 64 + rrow) * 128 + (ph0 ^ 64);

  const f32x4 fzero = {0.f, 0.f, 0.f, 0.f};
  f32x4 acc[4][4];
#pragma unroll
  for (int i = 0; i < 4; ++i)
#pragma unroll
    for (int j = 0; j < 4; ++j) acc[i][j] = fzero;

  // one K-step = 64 k-elems; stage = 8 GLD16 (A rows 0-127 in 4, B rows 0-127 in 4)
#define STG(kt, s) do { \
    char* d_ = lb + (s) * 32768; \
    const u16* a_ = Ag + (size_t)(kt) * 64; \
    const u16* b_ = Bg + (size_t)(kt) * 64; \
    GLD16(a_,             d_ + tid * 16); \
    GLD16(a_ + rstep,     d_ + 4096 + tid * 16); \
    GLD16(a_ + 2 * rstep, d_ + 8192 + tid * 16); \
    GLD16(a_ + 3 * rstep, d_ + 12288 + tid * 16); \
    GLD16(b_,             d_ + 16384 + tid * 16); \
    GLD16(b_ + rstep,     d_ + 20480 + tid * 16); \
    GLD16(b_ + 2 * rstep, d_ + 24576 + tid * 16); \
    GLD16(b_ + 3 * rstep, d_ + 28672 + tid * 16); \
  } while (0)

  const int nk = K >> 6;
  STG(0, 0);
  __syncthreads();
  for (int kt = 0; kt < nk; ++kt) {
    if (kt + 1 < nk) STG(kt + 1, (kt + 1) & 1);
    const char* sb = lb + (kt & 1) * 32768;
    // ---- k-chunk 0
    bf16x8 af[4], bfr[4];
#pragma unroll
    for (int mf = 0; mf < 4; ++mf)
      af[mf] = *(const bf16x8*)(sb + aoff0 + mf * 2048);
#pragma unroll
    for (int nf = 0; nf < 4; ++nf)
      bfr[nf] = *(const bf16x8*)(sb + boff0 + nf * 2048);
#pragma unroll
    for (int mf = 0; mf < 4; ++mf)
#pragma unroll
      for (int nf = 0; nf < 4; ++nf)
        acc[mf][nf] = MM(af[mf], bfr[nf], acc[mf][nf]);
    // ---- k-chunk 1
#pragma unroll
    for (int mf = 0; mf < 4; ++mf)
      af[mf] = *(const bf16x8*)(sb + aoff1 + mf * 2048);
#pragma unroll
    for (int nf = 0; nf < 4; ++nf)
      bfr[nf] = *(const bf16x8*)(sb + boff1 + nf * 2048);
#pragma unroll
    for (int mf = 0; mf < 4; ++mf)
#pragma unroll
      for (int nf = 0; nf < 4; ++nf)
        acc[mf][nf] = MM(af[mf], bfr[nf], acc[mf][nf]);
    __syncthreads();
  }
#undef STG

  const int g4 = (lane >> 4) << 2;
#pragma unroll
  for (int nf = 0; nf < 4; ++nf) {
    const int col = n0 + wn * 64 + nf * 16 + rrow;
    const float bvb = bias[col];
    const float csf = (EPI == 0 && col < qlimit) ? qscale : 1.0f;
#pragma unroll
    for (int mf = 0; mf < 4; ++mf) {
#pragma unroll
      for (int r = 0; r < 4; ++r) {
        const int row = m0 + wm * 64 + mf * 16 + g4 + r;
        float v = acc[mf][nf][r] + bvb;
        if (EPI == 0) v *= csf;
        if (EPI == 1) v = 0.5f * v * (1.0f + erff(v * 0.70710678118654752f));
        if (EPI == 2) {
          v += res[(size_t)row * Ndim + col];
          ((float*)Cout)[(size_t)row * Ndim + col] = v;
        } else {
          ((u16*)Cout)[(size_t)row * Ndim + col] = f2bf(v);
        }
      }
    }
  }
}

// ---------------- V transpose: qkv V block -> vt[bh][d][n] bf16 --------------------
__global__ __launch_bounds__(256) void vtrans(const u16* __restrict__ qkv,
                                              u16* __restrict__ vt) {
  const int bh = blockIdx.y, b = bh >> 4, h = bh & 15;
  const int n0 = blockIdx.x << 6;
  __shared__ __align__(16) u16 tile[64][72];
  const int t = threadIdx.x, r = t >> 2, c = t & 3;
  const u16* src = qkv + (size_t)((b << 10) + n0 + r) * 3072 + 2048 + (h << 6);
#pragma unroll
  for (int p = 0; p < 2; ++p)
    *(uint4*)&tile[r][(c * 2 + p) * 8] = *(const uint4*)(src + (c * 2 + p) * 8);
  __syncthreads();
  u16* dst = vt + (size_t)((bh << 6) + r) * 1024 + n0;
#pragma unroll
  for (int p = 0; p < 2; ++p) {
    u16 o[8];
#pragma unroll
    for (int j = 0; j < 8; ++j) o[j] = tile[(c * 2 + p) * 8 + j][r];
    uint4 w;
    w.x = (uint32_t)o[0] | ((uint32_t)o[1] << 16);
    w.y = (uint32_t)o[2] | ((uint32_t)o[3] << 16);
    w.z = (uint32_t)o[4] | ((uint32_t)o[5] << 16);
    w.w = (uint32_t)o[6] | ((uint32_t)o[7] << 16);
    *(uint4*)&dst[(c * 2 + p) * 8] = w;
  }
}

// ---------------- flash attention (no-max softmax, swapped QK^T) -------------------
__global__ __launch_bounds__(256) void attn64(const u16* __restrict__ qkv,
                                              const u16* __restrict__ vt,
                                              u16* __restrict__ aout) {
  const int bh = blockIdx.y, b = bh >> 4, h = bh & 15;
  const int q0 = blockIdx.x << 6;
  const int tid = threadIdx.x, lane = tid & 63, wid = tid >> 6;
  __shared__ __align__(16) u16 kl[4096];
  __shared__ __align__(16) u16 vl[4096];
  __shared__ __align__(16) u16 pl[4][1152];  // [wave][16 q][72]: P rows, k-major

  const int rrow = lane & 15;
  const int g = lane >> 4;
  const u16* qrow = qkv + (size_t)((b << 10) + q0 + (wid << 4) + rrow) * 3072 + (h << 6);
  bf16x8 qf0 = *(const bf16x8*)(qrow + (g << 3));
  bf16x8 qf1 = *(const bf16x8*)(qrow + 32 + (g << 3));

  const int sr = lane >> 3;
  const int lc = (lane & 7) ^ sr;
  const u16* kbase = qkv + (size_t)(b << 10) * 3072 + 1024 + (h << 6) +
                     (size_t)(16 * wid + sr) * 3072 + lc * 8;
  const u16* vbase = vt + (size_t)(bh << 6) * 1024 + (size_t)(16 * wid + sr) * 1024 + lc * 8;

  const f32x4 fzero = {0.f, 0.f, 0.f, 0.f};
  f32x4 oacc[4];
#pragma unroll
  for (int i = 0; i < 4; ++i) oacc[i] = fzero;
  f32x4 lacc = fzero;
  const int rcb = lane & 7;
  u16* plw = &pl[wid][0];

  for (int t = 0; t < 16; ++t) {
    const int kt0 = t << 6;
    GLD16(kbase + (size_t)kt0 * 3072, &kl[(2 * wid + 0) * 512]);
    GLD16(kbase + (size_t)kt0 * 3072 + 8 * 3072, &kl[(2 * wid + 1) * 512]);
    GLD16(vbase + kt0, &vl[(2 * wid + 0) * 512]);
    GLD16(vbase + kt0 + 8 * 1024, &vl[(2 * wid + 1) * 512]);
    __syncthreads();

    f32x4 s4[4];
#pragma unroll
    for (int i = 0; i < 4; ++i) s4[i] = fzero;
#pragma unroll
    for (int nf = 0; nf < 4; ++nf) {
      bf16x8 k0 = *(const bf16x8*)((const char*)kl + (nf * 16 + rrow) * 128 +
                                   ((g + 0) ^ rcb) * 16);
      bf16x8 k1 = *(const bf16x8*)((const char*)kl + (nf * 16 + rrow) * 128 +
                                   ((g + 4) ^ rcb) * 16);
      s4[nf] = __builtin_amdgcn_mfma_f32_16x16x32_bf16(k0, qf0, s4[nf], 0, 0, 0);
      s4[nf] = __builtin_amdgcn_mfma_f32_16x16x32_bf16(k1, qf1, s4[nf], 0, 0, 0);
    }

#pragma unroll
    for (int nf = 0; nf < 4; ++nf) {
      float p0 = exp2f(s4[nf][0]);
      float p1 = exp2f(s4[nf][1]);
      float p2 = exp2f(s4[nf][2]);
      float p3 = exp2f(s4[nf][3]);
      f32x4 pv = {p0, p1, p2, p3};
      lacc += pv;
      uint32_t a0 = __builtin_bit_cast(uint32_t, p0) + 0x8000u;
      uint32_t a1 = __builtin_bit_cast(uint32_t, p1) + 0x8000u;
      uint32_t a2 = __builtin_bit_cast(uint32_t, p2) + 0x8000u;
      uint32_t a3 = __builtin_bit_cast(uint32_t, p3) + 0x8000u;
      uint2 w;
      w.x = __builtin_amdgcn_perm(a1, a0, 0x07060302);
      w.y = __builtin_amdgcn_perm(a3, a2, 0x07060302);
      *(uint2*)(plw + rrow * 72 + nf * 16 + (g << 2)) = w;
    }

    bf16x8 pf0 = *(const bf16x8*)((const char*)plw + rrow * 144 + (g << 4));
    bf16x8 pf1 = *(const bf16x8*)((const char*)plw + rrow * 144 + (g << 4) + 64);
#pragma unroll
    for (int nf = 0; nf < 4; ++nf) {
      bf16x8 v0 = *(const bf16x8*)((const char*)vl + (nf * 16 + rrow) * 128 +
                                   ((g + 0) ^ rcb) * 16);
      bf16x8 v1 = *(const bf16x8*)((const char*)vl + (nf * 16 + rrow) * 128 +
                                   ((g + 4) ^ rcb) * 16);
      oacc[nf] = __builtin_amdgcn_mfma_f32_16x16x32_bf16(pf0, v0, oacc[nf], 0, 0, 0);
      oacc[nf] = __builtin_amdgcn_mfma_f32_16x16x32_bf16(pf1, v1, oacc[nf], 0, 0, 0);
    }
    __syncthreads();
  }

  float lsum = lacc[0] + lacc[1] + lacc[2] + lacc[3];
  lsum += __shfl_xor(lsum, 16);
  lsum += __shfl_xor(lsum, 32);
  const float inv = 1.0f / lsum;
  float invq[4];
#pragma unroll
  for (int r = 0; r < 4; ++r) {
    int bi = __builtin_amdgcn_ds_bpermute(((g << 2) + r) << 2,
                                          __builtin_bit_cast(int, inv));
    invq[r] = __builtin_bit_cast(float, bi);
  }
  u16* ob = aout + (size_t)((b << 10) + q0 + (wid << 4)) * 1024 + (h << 6);
#pragma unroll
  for (int nf = 0; nf < 4; ++nf)
#pragma unroll
    for (int r = 0; r < 4; ++r)
      ob[(size_t)(g * 4 + r) * 1024 + nf * 16 + rrow] = f2bf(oacc[nf][r] * invq[r]);
}

// ---------------- launcher ---------------------------------------------------------
extern "C" void kernel_launch(void* const* d_in, const int* in_sizes, int n_in,
                              void* d_out, int out_size, void* d_ws, size_t ws_size,
                              hipStream_t stream) {
  const float* x = (const float*)d_in[0];
  const float* ln1_g = (const float*)d_in[1];
  const float* ln1_b = (const float*)d_in[2];
  const float* w_qkv = (const float*)d_in[3];
  const float* b_qkv = (const float*)d_in[4];
  const float* w_o = (const float*)d_in[5];
  const float* b_o = (const float*)d_in[6];
  const float* ln2_g = (const float*)d_in[7];
  const float* ln2_b = (const float*)d_in[8];
  const float* w_fc1 = (const float*)d_in[9];
  const float* b_fc1 = (const float*)d_in[10];
  const float* w_fc2 = (const float*)d_in[11];
  const float* b_fc2 = (const float*)d_in[12];
  float* out = (float*)d_out;

  char* w = (char*)d_ws;
  u16* wqkvT = (u16*)w; w += (size_t)3072 * 1024 * 2;
  u16* woT   = (u16*)w; w += (size_t)1024 * 1024 * 2;
  u16* wfc1T = (u16*)w; w += (size_t)4096 * 1024 * 2;
  u16* wfc2T = (u16*)w; w += (size_t)1024 * 4096 * 2;
  u16* xn    = (u16*)w; w += (size_t)8192 * 1024 * 2;
  u16* qkvb  = (u16*)w; w += (size_t)8192 * 3072 * 2;
  u16* vtb   = (u16*)w; w += (size_t)128 * 64 * 1024 * 2;
  u16* attnb = (u16*)w; w += (size_t)8192 * 1024 * 2;
  u16* hbuf  = qkvb;  // overlay: qkv+vt dead when h is produced

  const float QS = 0.18033688011112042f;  // 0.125 * log2(e)

  wtrans<<<dim3(48, 16), 256, 0, stream>>>(w_qkv, wqkvT, 1024, 3072);
  wtrans<<<dim3(16, 16), 256, 0, stream>>>(w_o, woT, 1024, 1024);
  wtrans<<<dim3(64, 16), 256, 0, stream>>>(w_fc1, wfc1T, 1024, 4096);
  wtrans<<<dim3(16, 64), 256, 0, stream>>>(w_fc2, wfc2T, 4096, 1024);

  lnorm<<<2048, 256, 0, stream>>>(x, ln1_g, ln1_b, xn);
  g97<0><<<1536, 256, 0, stream>>>(xn, wqkvT, b_qkv, nullptr, qkvb, 3072, 1024, QS, 1024, 24);
  vtrans<<<dim3(16, 128), 256, 0, stream>>>(qkvb, vtb);
  attn64<<<dim3(16, 128), 256, 0, stream>>>(qkvb, vtb, attnb);
  g97<2><<<512, 256, 0, stream>>>(attnb, woT, b_o, x, out, 1024, 1024, 1.f, 0, 8);
  lnorm<<<2048, 256, 0, stream>>>(out, ln2_g, ln2_b, xn);
  g97<1><<<2048, 256, 0, stream>>>(xn, wfc1T, b_fc1, nullptr, hbuf, 4096, 1024, 1.f, 0, 32);
  g97<2><<<512, 256, 0, stream>>>(hbuf, wfc2T, b_fc2, out, out, 1024, 4096, 1.f, 0, 8);
}